// Round 3
// baseline (108.506 us; speedup 1.0000x reference)
//
#include <hip/hip_runtime.h>
#include <hip/hip_bf16.h>

typedef unsigned int uint32;
typedef unsigned short u16;

#define NPT 128        // grid nodes per dim
#define RNK 16         // TT rank
// Mid-core LDS row: 256 bf16 payload + pad -> 520 B stride (130 u32, 130%32==2)
// -> row starts hit 16 distinct even bank positions (vs 8 groups with 16B-aligned strides)
#define MIDROW_U16 260
#define MIDROW_U32 130
#define EDGEROW 20     // fp32 elems per LDS row for edge cores (16 + 4 pad) = 80 B
#define SMEM_G (NPT*MIDROW_U16*2 + 2*NPT*EDGEROW*4)    // c1 + edges        = 87040 B
#define SMEM_L (2*NPT*MIDROW_U16*2 + 2*NPT*EDGEROW*4)  // c1 + c2 + edges   = 153600 B
#define WS_NEEDED (RNK*NPT*RNK*2)                      // core2 as bf16 = 65536 B

#if defined(__has_builtin)
#if __has_builtin(__builtin_amdgcn_fdot2_f32_bf16)
#define HAVE_BFDOT2 1
#endif
#endif

__device__ __forceinline__ float bl(uint32 u){ return __uint_as_float(u << 16); }
__device__ __forceinline__ float bh(uint32 u){ return __uint_as_float(u & 0xffff0000u); }

#ifdef HAVE_BFDOT2
typedef __bf16 v2bf __attribute__((ext_vector_type(2)));
__device__ __forceinline__ v2bf bc(uint32 u){ return __builtin_bit_cast(v2bf, u); }

// dot of packed-bf16 v (8 u32) with 16 bf16 core elems in 8 u32
__device__ __forceinline__ float dot16b(const uint32* vp, const uint32* u) {
  float s0 = 0.f, s1 = 0.f;
#pragma unroll
  for (int k = 0; k < 4; ++k) {
    s0 = __builtin_amdgcn_fdot2_f32_bf16(bc(vp[k]),   bc(u[k]),   s0, false);
    s1 = __builtin_amdgcn_fdot2_f32_bf16(bc(vp[4+k]), bc(u[4+k]), s1, false);
  }
  return s0 + s1;
}
#else
__device__ __forceinline__ float dot16f(const float* v, const uint32* u) {
  float s0 = 0.f, s1 = 0.f;
#pragma unroll
  for (int k = 0; k < 4; ++k) {
    s0 = fmaf(v[2*k],   bl(u[k]),   s0); s0 = fmaf(v[2*k+1],   bh(u[k]),   s0);
    s1 = fmaf(v[8+2*k], bl(u[4+k]), s1); s1 = fmaf(v[9+2*k],   bh(u[4+k]), s1);
  }
  return s0 + s1;
}
#endif

struct VPack {
#ifdef HAVE_BFDOT2
  uint32 p[8];
  __device__ __forceinline__ void pack(const float v[16]) {
#pragma unroll
    for (int k = 0; k < 8; ++k) {
      __hip_bfloat16 l = __float2bfloat16(v[2*k]);
      __hip_bfloat16 h = __float2bfloat16(v[2*k+1]);
      p[k] = (uint32)(*(u16*)&l) | ((uint32)(*(u16*)&h) << 16);
    }
  }
  __device__ __forceinline__ float dot(const float* v, const uint32* u) const {
    (void)v; return dot16b(p, u);
  }
#else
  __device__ __forceinline__ void pack(const float v[16]) {}
  __device__ __forceinline__ float dot(const float* v, const uint32* u) const {
    return dot16f(v, u);
  }
#endif
};

// middle-dim contraction from LDS, ds_read_b64 granularity (520 B row stride)
__device__ __forceinline__ void tt_mid_lds(const uint32* __restrict__ base, float xc, float v[16]) {
  int n0 = (int)xc;
  float w = xc - (float)n0;
  int n1 = min(n0 + 1, NPT - 1);
  const uint32* r0 = base + n0 * MIDROW_U32;
  const uint32* r1 = base + n1 * MIDROW_U32;
  VPack vp; vp.pack(v);
  float nv[16];
#pragma unroll
  for (int j = 0; j < 16; ++j) {
    uint32 A[8], B[8];
    const uint2* q0 = (const uint2*)(r0 + j * 8);
    const uint2* q1 = (const uint2*)(r1 + j * 8);
#pragma unroll
    for (int m = 0; m < 4; ++m) {
      uint2 a = q0[m]; A[2*m] = a.x; A[2*m+1] = a.y;
      uint2 b = q1[m]; B[2*m] = b.x; B[2*m+1] = b.y;
    }
    float a = vp.dot(v, A);
    float b = vp.dot(v, B);
    nv[j] = fmaf(w, b - a, a);
  }
#pragma unroll
  for (int j = 0; j < 16; ++j) v[j] = nv[j];
}

// middle-dim contraction from global (L2-resident bf16 [n][j*16+i], 512 B rows, no pad)
__device__ __forceinline__ void tt_mid_glb(const uint32* __restrict__ base, float xc, float v[16]) {
  int n0 = (int)xc;
  float w = xc - (float)n0;
  int n1 = min(n0 + 1, NPT - 1);
  const uint32* r0 = base + n0 * 128;
  const uint32* r1 = base + n1 * 128;
  VPack vp; vp.pack(v);
  float nv[16];
#pragma unroll
  for (int j = 0; j < 16; ++j) {
    uint32 A[8], B[8];
    const uint4* q0 = (const uint4*)(r0 + j * 8);
    const uint4* q1 = (const uint4*)(r1 + j * 8);
    uint4 a0 = q0[0], a1 = q0[1];
    uint4 b0 = q1[0], b1 = q1[1];
    A[0]=a0.x; A[1]=a0.y; A[2]=a0.z; A[3]=a0.w; A[4]=a1.x; A[5]=a1.y; A[6]=a1.z; A[7]=a1.w;
    B[0]=b0.x; B[1]=b0.y; B[2]=b0.z; B[3]=b0.w; B[4]=b1.x; B[5]=b1.y; B[6]=b1.z; B[7]=b1.w;
    float a = vp.dot(v, A);
    float b = vp.dot(v, B);
    nv[j] = fmaf(w, b - a, a);
  }
#pragma unroll
  for (int j = 0; j < 16; ++j) v[j] = nv[j];
}

__device__ __forceinline__ float remap_clamp(float x) {
  float xr = (x + 1.0f) * 0.5f * (float)(NPT - 1);
  return fminf(fmaxf(xr, 0.0f), (float)(NPT - 1));
}

// prep: core2 fp32 [i][n][j] -> ws bf16 [n][j*16+i], u32-paired coalesced writes
__global__ void prep_c2(const float* __restrict__ g2, uint32* __restrict__ ws) {
  int o2 = blockIdx.x * blockDim.x + threadIdx.x;   // 16384 items
  int o = o2 * 2;
  int n = o >> 8, j = (o >> 4) & 15, i = o & 15;
  __hip_bfloat16 l = __float2bfloat16(g2[i * 2048 + n * 16 + j]);
  __hip_bfloat16 h = __float2bfloat16(g2[(i + 1) * 2048 + n * 16 + j]);
  ws[o2] = (uint32)(*(u16*)&l) | ((uint32)(*(u16*)&h) << 16);
}

template <bool C2GLOBAL>
__global__ __launch_bounds__(1024, 4) void tt_kernel(
    const float* __restrict__ x,  const float* __restrict__ g0,
    const float* __restrict__ g1, const float* __restrict__ g2,
    const float* __restrict__ g3, const uint32* __restrict__ wsc2,
    float* __restrict__ out, int npts)
{
  extern __shared__ char smem[];
  u16* c1 = (u16*)smem;                                   // [128][260] bf16
  u16* c2 = C2GLOBAL ? nullptr : c1 + NPT * MIDROW_U16;   // [128][260] bf16 (fallback only)
  float* c0 = (float*)(smem + (C2GLOBAL ? NPT*MIDROW_U16*2 : 2*NPT*MIDROW_U16*2));
  float* c3 = c0 + NPT * EDGEROW;

  // Stage mid core(s): global [i][n][j] fp32 -> LDS [n][j*16+i] bf16 (RNE)
  for (int t = threadIdx.x; t < RNK * NPT * RNK; t += blockDim.x) {
    int i = t >> 11;
    int n = (t >> 4) & (NPT - 1);
    int j = t & (RNK - 1);
    __hip_bfloat16 h1 = __float2bfloat16(g1[t]);
    c1[n * MIDROW_U16 + j * 16 + i] = *(u16*)&h1;
    if (!C2GLOBAL) {
      __hip_bfloat16 h2 = __float2bfloat16(g2[t]);
      c2[n * MIDROW_U16 + j * 16 + i] = *(u16*)&h2;
    }
  }
  // Stage edge cores (fp32): core0 [1][n][j] -> [n][j]; core3 [i][n][1] -> [n][i]
  for (int t = threadIdx.x; t < NPT * RNK; t += blockDim.x) {
    int n = t >> 4;
    int i = t & (RNK - 1);
    c0[n * EDGEROW + i] = g0[t];
    c3[n * EDGEROW + i] = g3[i * NPT + n];
  }
  __syncthreads();

  int p = blockIdx.x * blockDim.x + threadIdx.x;
  if (p >= npts) return;
  float4 xv = reinterpret_cast<const float4*>(x)[p];

  float v[16];
  // dim 0
  {
    float xc = remap_clamp(xv.x);
    int n0 = (int)xc; float w = xc - (float)n0; int n1 = min(n0 + 1, NPT - 1);
    const float4* L = (const float4*)(c0 + n0 * EDGEROW);
    const float4* H = (const float4*)(c0 + n1 * EDGEROW);
#pragma unroll
    for (int k = 0; k < 4; ++k) {
      float4 l = L[k], h = H[k];
      v[4*k+0] = fmaf(w, h.x - l.x, l.x);
      v[4*k+1] = fmaf(w, h.y - l.y, l.y);
      v[4*k+2] = fmaf(w, h.z - l.z, l.z);
      v[4*k+3] = fmaf(w, h.w - l.w, l.w);
    }
  }
  // dims 1, 2
  tt_mid_lds((const uint32*)c1, remap_clamp(xv.y), v);
  if (C2GLOBAL) tt_mid_glb(wsc2, remap_clamp(xv.z), v);
  else          tt_mid_lds((const uint32*)c2, remap_clamp(xv.z), v);
  // dim 3
  float acc;
  {
    float xc = remap_clamp(xv.w);
    int n0 = (int)xc; float w = xc - (float)n0; int n1 = min(n0 + 1, NPT - 1);
    const float4* L = (const float4*)(c3 + n0 * EDGEROW);
    const float4* H = (const float4*)(c3 + n1 * EDGEROW);
    float a0 = 0.f, a1 = 0.f, a2 = 0.f, a3 = 0.f;
#pragma unroll
    for (int k = 0; k < 4; ++k) {
      float4 l = L[k], h = H[k];
      a0 = fmaf(v[4*k+0], fmaf(w, h.x - l.x, l.x), a0);
      a1 = fmaf(v[4*k+1], fmaf(w, h.y - l.y, l.y), a1);
      a2 = fmaf(v[4*k+2], fmaf(w, h.z - l.z, l.z), a2);
      a3 = fmaf(v[4*k+3], fmaf(w, h.w - l.w, l.w), a3);
    }
    acc = (a0 + a1) + (a2 + a3);
  }
  out[p] = acc;
}

extern "C" void kernel_launch(void* const* d_in, const int* in_sizes, int n_in,
                              void* d_out, int out_size, void* d_ws, size_t ws_size,
                              hipStream_t stream) {
  const float* x  = (const float*)d_in[0];
  const float* g0 = (const float*)d_in[1];
  const float* g1 = (const float*)d_in[2];
  const float* g2 = (const float*)d_in[3];
  const float* g3 = (const float*)d_in[4];
  float* out = (float*)d_out;

  int B = in_sizes[0] / 4;
  int block = 1024;
  int grid = (B + block - 1) / block;   // 256 blocks -> 1 per CU

  if (ws_size >= WS_NEEDED) {
    hipFuncSetAttribute(reinterpret_cast<const void*>(tt_kernel<true>),
                        hipFuncAttributeMaxDynamicSharedMemorySize, SMEM_G);
    prep_c2<<<64, 256, 0, stream>>>(g2, (uint32*)d_ws);
    tt_kernel<true><<<grid, block, SMEM_G, stream>>>(
        x, g0, g1, g2, g3, (const uint32*)d_ws, out, B);
  } else {
    hipFuncSetAttribute(reinterpret_cast<const void*>(tt_kernel<false>),
                        hipFuncAttributeMaxDynamicSharedMemorySize, SMEM_L);
    tt_kernel<false><<<grid, block, SMEM_L, stream>>>(
        x, g0, g1, g2, g3, nullptr, out, B);
  }
}

// Round 4
// 85.467 us; speedup vs baseline: 1.2696x; 1.2696x over previous
//
#include <hip/hip_runtime.h>
#include <hip/hip_bf16.h>

typedef unsigned int uint32;
typedef unsigned short u16;

#define NPT 128        // grid nodes per dim
#define RNK 16         // TT rank
#define ROW_U16 256    // mid-core row = 512 B, NO pad: bank tiling comes from 8-lane cooperation
#define EDGEROW 20     // fp32 elems per edge row (16 + 4 pad) = 80 B
#define NWAVES 16
// c1 + c2 (131072) + edges (20480) + exchange scratch (4096) = 155648 B
#define SMEM_BYTES (2*NPT*ROW_U16*2 + 2*NPT*EDGEROW*4 + NWAVES*64*4)

#if defined(__has_builtin)
#if __has_builtin(__builtin_amdgcn_fdot2_f32_bf16)
#define HAVE_BFDOT2 1
#endif
#endif

__device__ __forceinline__ float bl(uint32 u){ return __uint_as_float(u << 16); }
__device__ __forceinline__ float bh(uint32 u){ return __uint_as_float(u & 0xffff0000u); }

#ifdef HAVE_BFDOT2
typedef __bf16 v2bf __attribute__((ext_vector_type(2)));
__device__ __forceinline__ v2bf bc(uint32 u){ return __builtin_bit_cast(v2bf, u); }
__device__ __forceinline__ float dot8(const uint32* vp, uint4 U) {
  float s = 0.f;
  s = __builtin_amdgcn_fdot2_f32_bf16(bc(vp[0]), bc(U.x), s, false);
  s = __builtin_amdgcn_fdot2_f32_bf16(bc(vp[1]), bc(U.y), s, false);
  s = __builtin_amdgcn_fdot2_f32_bf16(bc(vp[2]), bc(U.z), s, false);
  s = __builtin_amdgcn_fdot2_f32_bf16(bc(vp[3]), bc(U.w), s, false);
  return s;
}
#else
__device__ __forceinline__ float dot8(const uint32* vp, uint4 U) {
  float s = fmaf(bh(vp[0]), bh(U.x), bl(vp[0]) * bl(U.x));
  s = fmaf(bl(vp[1]), bl(U.y), s); s = fmaf(bh(vp[1]), bh(U.y), s);
  s = fmaf(bl(vp[2]), bl(U.z), s); s = fmaf(bh(vp[2]), bh(U.z), s);
  s = fmaf(bl(vp[3]), bl(U.w), s); s = fmaf(bh(vp[3]), bh(U.w), s);
  return s;
}
#endif

__device__ __forceinline__ uint32 packbf(float a, float b) {
  __hip_bfloat16 l = __float2bfloat16(a), h = __float2bfloat16(b);
  return (uint32)(*(u16*)&l) | ((uint32)(*(u16*)&h) << 16);
}

__device__ __forceinline__ float remap_clamp(float x) {
  float xr = (x + 1.0f) * 0.5f * (float)(NPT - 1);
  return fminf(fmaxf(xr, 0.0f), (float)(NPT - 1));
}

// One mid-dim contraction, lane q of the point's 8-lane group.
// LDS row layout (u16): off = n*256 + slot*8 + (i&7), slot = (j>>1) + 8*(i>>3) + 16*(j&1)
// => lane q's fragments for cols {2q,2q+1} are at bytes q*16 + {0,128,256,384}:
//    each wave-level ds_read_b128 hits every bank exactly 8x -> zero conflicts.
__device__ __forceinline__ void mid_dim(const u16* __restrict__ c, float xc, int q,
                                        const uint32* vp, float& nv0, float& nv1)
{
  int n0 = (int)xc;
  float w = xc - (float)n0;
  int n1 = min(n0 + 1, NPT - 1);
  const uint32* r0 = (const uint32*)(c + n0 * ROW_U16) + q * 4;
  const uint32* r1 = (const uint32*)(c + n1 * ROW_U16) + q * 4;
  uint4 A0 = *(const uint4*)(r0);        // col 2q,   i 0-7,  row n0
  uint4 B0 = *(const uint4*)(r0 + 32);   // col 2q,   i 8-15, row n0
  uint4 C0 = *(const uint4*)(r0 + 64);   // col 2q+1, i 0-7,  row n0
  uint4 D0 = *(const uint4*)(r0 + 96);   // col 2q+1, i 8-15, row n0
  uint4 A1 = *(const uint4*)(r1);
  uint4 B1 = *(const uint4*)(r1 + 32);
  uint4 C1 = *(const uint4*)(r1 + 64);
  uint4 D1 = *(const uint4*)(r1 + 96);
  float a0 = dot8(vp, A0) + dot8(vp + 4, B0);
  float a1 = dot8(vp, A1) + dot8(vp + 4, B1);
  float b0 = dot8(vp, C0) + dot8(vp + 4, D0);
  float b1 = dot8(vp, C1) + dot8(vp + 4, D1);
  nv0 = fmaf(w, a1 - a0, a0);
  nv1 = fmaf(w, b1 - b0, b0);
}

// All-gather the point's v (16 floats spread 2-per-lane) as packed bf16 pairs.
// Write: 64 consecutive u32 per wave (conflict-free). Read: 16B broadcast per point.
__device__ __forceinline__ void exchange(uint32* myxch, int lane,
                                         float nv0, float nv1, uint32* vp)
{
  myxch[lane] = packbf(nv0, nv1);
  __asm__ volatile("s_waitcnt lgkmcnt(0)" ::: "memory");
  const uint4* b = (const uint4*)(myxch + (lane & 56));
  uint4 w0 = b[0], w1 = b[1];
  vp[0] = w0.x; vp[1] = w0.y; vp[2] = w0.z; vp[3] = w0.w;
  vp[4] = w1.x; vp[5] = w1.y; vp[6] = w1.z; vp[7] = w1.w;
}

__global__ __launch_bounds__(1024, 4) void tt_kernel(
    const float* __restrict__ x,  const float* __restrict__ g0,
    const float* __restrict__ g1, const float* __restrict__ g2,
    const float* __restrict__ g3, float* __restrict__ out, int npts)
{
  extern __shared__ char smem[];
  u16* c1 = (u16*)smem;                          // [128][256] bf16 swizzled
  u16* c2 = c1 + NPT * ROW_U16;                  // [128][256] bf16 swizzled
  float* c0 = (float*)(c2 + NPT * ROW_U16);      // [128][20] fp32
  float* c3 = c0 + NPT * EDGEROW;                // [128][20] fp32
  uint32* xch = (uint32*)(c3 + NPT * EDGEROW);   // [16 waves][64] u32

  // Stage mid cores: global [i][n][j] fp32 -> swizzled LDS bf16
  for (int t = threadIdx.x; t < RNK * NPT * RNK; t += blockDim.x) {
    int i = t >> 11;
    int n = (t >> 4) & (NPT - 1);
    int j = t & (RNK - 1);
    int slot = (j >> 1) + ((i >> 3) << 3) + ((j & 1) << 4);
    int off = n * ROW_U16 + slot * 8 + (i & 7);
    __hip_bfloat16 h1 = __float2bfloat16(g1[t]);
    __hip_bfloat16 h2 = __float2bfloat16(g2[t]);
    c1[off] = *(u16*)&h1;
    c2[off] = *(u16*)&h2;
  }
  // Edge cores (fp32): core0 [1][n][j] -> [n][j]; core3 [i][n][1] -> [n][i]
  for (int t = threadIdx.x; t < NPT * RNK; t += blockDim.x) {
    int n = t >> 4;
    int i = t & (RNK - 1);
    c0[n * EDGEROW + i] = g0[t];
    c3[n * EDGEROW + i] = g3[i * NPT + n];
  }
  __syncthreads();

  const int lane = threadIdx.x & 63;
  const int q = threadIdx.x & 7;
  uint32* myxch = xch + (threadIdx.x >> 6) * 64;
  const int ptb = threadIdx.x >> 3;              // 0..127 point slot in block

  for (int it = 0; it < 8; ++it) {
    int p = (blockIdx.x << 10) + (it << 7) + ptb;
    if (p >= npts) break;
    float4 xv = reinterpret_cast<const float4*>(x)[p];  // 8 lanes share -> L1 broadcast

    uint32 vp[8];
    float nv0, nv1;
    // dim 0: lane q produces v[2q], v[2q+1]
    {
      float xc = remap_clamp(xv.x);
      int n0 = (int)xc; float w = xc - (float)n0; int n1 = min(n0 + 1, NPT - 1);
      float2 lo = *(const float2*)(c0 + n0 * EDGEROW + 2 * q);
      float2 hi = *(const float2*)(c0 + n1 * EDGEROW + 2 * q);
      nv0 = fmaf(w, hi.x - lo.x, lo.x);
      nv1 = fmaf(w, hi.y - lo.y, lo.y);
    }
    exchange(myxch, lane, nv0, nv1, vp);
    mid_dim(c1, remap_clamp(xv.y), q, vp, nv0, nv1);
    exchange(myxch, lane, nv0, nv1, vp);
    mid_dim(c2, remap_clamp(xv.z), q, vp, nv0, nv1);
    // dim 3: partial product + 8-lane butterfly reduction
    {
      float xc = remap_clamp(xv.w);
      int n0 = (int)xc; float w = xc - (float)n0; int n1 = min(n0 + 1, NPT - 1);
      float2 lo = *(const float2*)(c3 + n0 * EDGEROW + 2 * q);
      float2 hi = *(const float2*)(c3 + n1 * EDGEROW + 2 * q);
      float m0 = fmaf(w, hi.x - lo.x, lo.x);
      float m1 = fmaf(w, hi.y - lo.y, lo.y);
      float part = fmaf(nv1, m1, nv0 * m0);
      part += __shfl_xor(part, 1, 64);
      part += __shfl_xor(part, 2, 64);
      part += __shfl_xor(part, 4, 64);
      if (q == 0) out[p] = part;   // 8 consecutive dwords per wave -> coalesced
    }
  }
}

extern "C" void kernel_launch(void* const* d_in, const int* in_sizes, int n_in,
                              void* d_out, int out_size, void* d_ws, size_t ws_size,
                              hipStream_t stream) {
  const float* x  = (const float*)d_in[0];
  const float* g0 = (const float*)d_in[1];
  const float* g1 = (const float*)d_in[2];
  const float* g2 = (const float*)d_in[3];
  const float* g3 = (const float*)d_in[4];
  float* out = (float*)d_out;

  int B = in_sizes[0] / 4;
  hipFuncSetAttribute(reinterpret_cast<const void*>(tt_kernel),
                      hipFuncAttributeMaxDynamicSharedMemorySize, SMEM_BYTES);
  int block = 1024;
  int grid = (B + 1024 - 1) / 1024;   // 256 blocks -> 1 per CU, 8 pts/wave-iter x 8 iters
  tt_kernel<<<grid, block, SMEM_BYTES, stream>>>(x, g0, g1, g2, g3, out, B);
}

// Round 5
// 83.805 us; speedup vs baseline: 1.2947x; 1.0198x over previous
//
#include <hip/hip_runtime.h>
#include <hip/hip_bf16.h>

typedef unsigned int uint32;
typedef unsigned short u16;

#define NPT 128        // grid nodes per dim
#define RNK 16         // TT rank
#define ROW_U16 256    // mid-core row = 512 B, NO pad: bank tiling via 8-lane cooperation
#define EDGEROW 20     // fp32 elems per edge row (16 + 4 pad) = 80 B
#define NWAVES 16
// c1+c2 (131072) + edges (20480) + 2x exchange scratch (8192) = 159744 B  (< 160 KiB)
#define SMEM_BYTES (2*NPT*ROW_U16*2 + 2*NPT*EDGEROW*4 + 2*NWAVES*64*4)

#if defined(__has_builtin)
#if __has_builtin(__builtin_amdgcn_fdot2_f32_bf16)
#define HAVE_BFDOT2 1
#endif
#endif

__device__ __forceinline__ float bl(uint32 u){ return __uint_as_float(u << 16); }
__device__ __forceinline__ float bh(uint32 u){ return __uint_as_float(u & 0xffff0000u); }

#ifdef HAVE_BFDOT2
typedef __bf16 v2bf __attribute__((ext_vector_type(2)));
__device__ __forceinline__ v2bf bc(uint32 u){ return __builtin_bit_cast(v2bf, u); }
__device__ __forceinline__ float dot8(const uint32* vp, uint4 U) {
  float s = 0.f;
  s = __builtin_amdgcn_fdot2_f32_bf16(bc(vp[0]), bc(U.x), s, false);
  s = __builtin_amdgcn_fdot2_f32_bf16(bc(vp[1]), bc(U.y), s, false);
  s = __builtin_amdgcn_fdot2_f32_bf16(bc(vp[2]), bc(U.z), s, false);
  s = __builtin_amdgcn_fdot2_f32_bf16(bc(vp[3]), bc(U.w), s, false);
  return s;
}
#else
__device__ __forceinline__ float dot8(const uint32* vp, uint4 U) {
  float s = fmaf(bh(vp[0]), bh(U.x), bl(vp[0]) * bl(U.x));
  s = fmaf(bl(vp[1]), bl(U.y), s); s = fmaf(bh(vp[1]), bh(U.y), s);
  s = fmaf(bl(vp[2]), bl(U.z), s); s = fmaf(bh(vp[2]), bh(U.z), s);
  s = fmaf(bl(vp[3]), bl(U.w), s); s = fmaf(bh(vp[3]), bh(U.w), s);
  return s;
}
#endif

__device__ __forceinline__ uint32 packbf(float a, float b) {
  __hip_bfloat16 l = __float2bfloat16(a), h = __float2bfloat16(b);
  return (uint32)(*(u16*)&l) | ((uint32)(*(u16*)&h) << 16);
}

__device__ __forceinline__ float remap_clamp(float x) {
  float xr = (x + 1.0f) * 0.5f * (float)(NPT - 1);
  return fminf(fmaxf(xr, 0.0f), (float)(NPT - 1));
}

// Two independent mid-dim contractions (points A,B), lane q of each 8-lane group.
// LDS row layout (u16): off = n*256 + slot*8 + (i&7), slot = (j>>1) + 8*(i>>3) + 16*(j&1)
// => lane q's fragments sit at bytes q*16 + {0,128,256,384}: every wave-level
// ds_read_b128 hits each bank exactly 8x -> zero conflicts for any random rows.
__device__ __forceinline__ void mid_dim2(const u16* __restrict__ c, float xcA, float xcB,
                                         int q, const uint32* vpA, const uint32* vpB,
                                         float& nA0, float& nA1, float& nB0, float& nB1)
{
  int a0 = (int)xcA; float wA = xcA - (float)a0; int a1 = min(a0 + 1, NPT - 1);
  int b0 = (int)xcB; float wB = xcB - (float)b0; int b1 = min(b0 + 1, NPT - 1);
  const uint32* rA0 = (const uint32*)(c + a0 * ROW_U16) + q * 4;
  const uint32* rA1 = (const uint32*)(c + a1 * ROW_U16) + q * 4;
  const uint32* rB0 = (const uint32*)(c + b0 * ROW_U16) + q * 4;
  const uint32* rB1 = (const uint32*)(c + b1 * ROW_U16) + q * 4;
  // issue all 16 loads (two independent chains for the scheduler)
  uint4 A0 = *(const uint4*)(rA0);      uint4 A1 = *(const uint4*)(rA0 + 32);
  uint4 A2 = *(const uint4*)(rA0 + 64); uint4 A3 = *(const uint4*)(rA0 + 96);
  uint4 A4 = *(const uint4*)(rA1);      uint4 A5 = *(const uint4*)(rA1 + 32);
  uint4 A6 = *(const uint4*)(rA1 + 64); uint4 A7 = *(const uint4*)(rA1 + 96);
  uint4 B0 = *(const uint4*)(rB0);      uint4 B1 = *(const uint4*)(rB0 + 32);
  uint4 B2 = *(const uint4*)(rB0 + 64); uint4 B3 = *(const uint4*)(rB0 + 96);
  uint4 B4 = *(const uint4*)(rB1);      uint4 B5 = *(const uint4*)(rB1 + 32);
  uint4 B6 = *(const uint4*)(rB1 + 64); uint4 B7 = *(const uint4*)(rB1 + 96);
  float aA0 = dot8(vpA, A0) + dot8(vpA + 4, A1);   // col 2q,   row lo
  float aA1 = dot8(vpA, A4) + dot8(vpA + 4, A5);   // col 2q,   row hi
  float bA0 = dot8(vpA, A2) + dot8(vpA + 4, A3);   // col 2q+1, row lo
  float bA1 = dot8(vpA, A6) + dot8(vpA + 4, A7);   // col 2q+1, row hi
  float aB0 = dot8(vpB, B0) + dot8(vpB + 4, B1);
  float aB1 = dot8(vpB, B4) + dot8(vpB + 4, B5);
  float bB0 = dot8(vpB, B2) + dot8(vpB + 4, B3);
  float bB1 = dot8(vpB, B6) + dot8(vpB + 4, B7);
  nA0 = fmaf(wA, aA1 - aA0, aA0);
  nA1 = fmaf(wA, bA1 - bA0, bA0);
  nB0 = fmaf(wB, aB1 - aB0, aB0);
  nB1 = fmaf(wB, bB1 - bB0, bB0);
}

// All-gather both points' v vectors (2 floats/lane each) as packed bf16 pairs.
// Two writes, ONE lgkmcnt drain, four b128 broadcast reads.
__device__ __forceinline__ void exchange2(uint32* xchA, uint32* xchB, int lane,
                                          float nA0, float nA1, float nB0, float nB1,
                                          uint32* vpA, uint32* vpB)
{
  xchA[lane] = packbf(nA0, nA1);
  xchB[lane] = packbf(nB0, nB1);
  __asm__ volatile("s_waitcnt lgkmcnt(0)" ::: "memory");
  const uint4* a = (const uint4*)(xchA + (lane & 56));
  const uint4* b = (const uint4*)(xchB + (lane & 56));
  uint4 a0 = a[0], a1 = a[1], b0 = b[0], b1 = b[1];
  vpA[0]=a0.x; vpA[1]=a0.y; vpA[2]=a0.z; vpA[3]=a0.w;
  vpA[4]=a1.x; vpA[5]=a1.y; vpA[6]=a1.z; vpA[7]=a1.w;
  vpB[0]=b0.x; vpB[1]=b0.y; vpB[2]=b0.z; vpB[3]=b0.w;
  vpB[4]=b1.x; vpB[5]=b1.y; vpB[6]=b1.z; vpB[7]=b1.w;
}

__global__ __launch_bounds__(1024, 4) void tt_kernel(
    const float* __restrict__ x,  const float* __restrict__ g0,
    const float* __restrict__ g1, const float* __restrict__ g2,
    const float* __restrict__ g3, float* __restrict__ out, int npts)
{
  extern __shared__ char smem[];
  u16* c1 = (u16*)smem;                          // [128][256] bf16 swizzled
  u16* c2 = c1 + NPT * ROW_U16;                  // [128][256] bf16 swizzled
  float* c0 = (float*)(c2 + NPT * ROW_U16);      // [128][20] fp32
  float* c3 = c0 + NPT * EDGEROW;                // [128][20] fp32
  uint32* xch = (uint32*)(c3 + NPT * EDGEROW);   // [16 waves][2][64] u32

  // Stage mid cores: global [i][n][j] fp32 -> swizzled LDS bf16
  for (int t = threadIdx.x; t < RNK * NPT * RNK; t += blockDim.x) {
    int i = t >> 11;
    int n = (t >> 4) & (NPT - 1);
    int j = t & (RNK - 1);
    int slot = (j >> 1) + ((i >> 3) << 3) + ((j & 1) << 4);
    int off = n * ROW_U16 + slot * 8 + (i & 7);
    __hip_bfloat16 h1 = __float2bfloat16(g1[t]);
    __hip_bfloat16 h2 = __float2bfloat16(g2[t]);
    c1[off] = *(u16*)&h1;
    c2[off] = *(u16*)&h2;
  }
  // Edge cores (fp32): core0 [1][n][j] -> [n][j]; core3 [i][n][1] -> [n][i]
  for (int t = threadIdx.x; t < NPT * RNK; t += blockDim.x) {
    int n = t >> 4;
    int i = t & (RNK - 1);
    c0[n * EDGEROW + i] = g0[t];
    c3[n * EDGEROW + i] = g3[i * NPT + n];
  }
  __syncthreads();

  const int lane = threadIdx.x & 63;
  const int q = threadIdx.x & 7;
  uint32* xchA = xch + (threadIdx.x >> 6) * 128;
  uint32* xchB = xchA + 64;
  const int ptb = threadIdx.x >> 3;              // 0..127 point slot in block

  for (int it = 0; it < 4; ++it) {
    int pA = (blockIdx.x << 10) + (it << 8) + ptb;
    int pB = pA + 128;
    bool okA = pA < npts, okB = pB < npts;
    float4 xvA = reinterpret_cast<const float4*>(x)[okA ? pA : 0];
    float4 xvB = reinterpret_cast<const float4*>(x)[okB ? pB : 0];

    uint32 vpA[8], vpB[8];
    float nA0, nA1, nB0, nB1;
    // dim 0: lane q produces v[2q], v[2q+1] for both points
    {
      float xcA = remap_clamp(xvA.x);
      int n0 = (int)xcA; float w = xcA - (float)n0; int n1 = min(n0 + 1, NPT - 1);
      float2 lo = *(const float2*)(c0 + n0 * EDGEROW + 2 * q);
      float2 hi = *(const float2*)(c0 + n1 * EDGEROW + 2 * q);
      nA0 = fmaf(w, hi.x - lo.x, lo.x);
      nA1 = fmaf(w, hi.y - lo.y, lo.y);
      float xcB = remap_clamp(xvB.x);
      int m0 = (int)xcB; float u = xcB - (float)m0; int m1 = min(m0 + 1, NPT - 1);
      float2 lo2 = *(const float2*)(c0 + m0 * EDGEROW + 2 * q);
      float2 hi2 = *(const float2*)(c0 + m1 * EDGEROW + 2 * q);
      nB0 = fmaf(u, hi2.x - lo2.x, lo2.x);
      nB1 = fmaf(u, hi2.y - lo2.y, lo2.y);
    }
    exchange2(xchA, xchB, lane, nA0, nA1, nB0, nB1, vpA, vpB);
    mid_dim2(c1, remap_clamp(xvA.y), remap_clamp(xvB.y), q, vpA, vpB, nA0, nA1, nB0, nB1);
    exchange2(xchA, xchB, lane, nA0, nA1, nB0, nB1, vpA, vpB);
    mid_dim2(c2, remap_clamp(xvA.z), remap_clamp(xvB.z), q, vpA, vpB, nA0, nA1, nB0, nB1);
    // dim 3: partial products + 8-lane butterfly reductions
    {
      float xcA = remap_clamp(xvA.w);
      int n0 = (int)xcA; float w = xcA - (float)n0; int n1 = min(n0 + 1, NPT - 1);
      float2 lo = *(const float2*)(c3 + n0 * EDGEROW + 2 * q);
      float2 hi = *(const float2*)(c3 + n1 * EDGEROW + 2 * q);
      float xcB = remap_clamp(xvB.w);
      int m0 = (int)xcB; float u = xcB - (float)m0; int m1 = min(m0 + 1, NPT - 1);
      float2 lo2 = *(const float2*)(c3 + m0 * EDGEROW + 2 * q);
      float2 hi2 = *(const float2*)(c3 + m1 * EDGEROW + 2 * q);
      float pa = fmaf(nA1, fmaf(w, hi.y - lo.y, lo.y), nA0 * fmaf(w, hi.x - lo.x, lo.x));
      float pb = fmaf(nB1, fmaf(u, hi2.y - lo2.y, lo2.y), nB0 * fmaf(u, hi2.x - lo2.x, lo2.x));
      pa += __shfl_xor(pa, 1, 64);  pb += __shfl_xor(pb, 1, 64);
      pa += __shfl_xor(pa, 2, 64);  pb += __shfl_xor(pb, 2, 64);
      pa += __shfl_xor(pa, 4, 64);  pb += __shfl_xor(pb, 4, 64);
      if (q == 0) {
        if (okA) out[pA] = pa;
        if (okB) out[pB] = pb;
      }
    }
  }
}

extern "C" void kernel_launch(void* const* d_in, const int* in_sizes, int n_in,
                              void* d_out, int out_size, void* d_ws, size_t ws_size,
                              hipStream_t stream) {
  const float* x  = (const float*)d_in[0];
  const float* g0 = (const float*)d_in[1];
  const float* g1 = (const float*)d_in[2];
  const float* g2 = (const float*)d_in[3];
  const float* g3 = (const float*)d_in[4];
  float* out = (float*)d_out;

  int B = in_sizes[0] / 4;
  hipFuncSetAttribute(reinterpret_cast<const void*>(tt_kernel),
                      hipFuncAttributeMaxDynamicSharedMemorySize, SMEM_BYTES);
  int block = 1024;
  int grid = (B + 1024 - 1) / 1024;   // 256 blocks -> 1/CU; 2-pt ILP x 4 iters x 128 groups
  tt_kernel<<<grid, block, SMEM_BYTES, stream>>>(x, g0, g1, g2, g3, out, B);
}